// Round 11
// baseline (33.626 us; speedup 1.0000x reference)
//
#include <hip/hip_runtime.h>
#include <math.h>

#define F 24
#define D 16
#define BATCH 2048
#define NPAIR 276
#define NTRIP 2024
#define VOCAB 10000

// ---- compile-time index algebra for lexicographic combinations ----
__host__ __device__ constexpr int pair_base(int i) { return i * 23 - i * (i - 1) / 2; }
__host__ __device__ constexpr int pair_idx(int i, int j) { return pair_base(i) + (j - i - 1); }
__host__ __device__ constexpr int trip_base(int i) {
    return NTRIP - (24 - i) * (23 - i) * (22 - i) / 6;
}
__host__ __device__ constexpr int trip_idx(int i, int j, int k) {
    return trip_base(i) + (j - i - 1) * (46 - i - j) / 2 + (k - j - 1);
}

// 16 contiguous pair-index chunks, balanced by trip count (~126 each)
constexpr int CHUNK_B[17] = {0, 7, 23, 30, 46, 54, 70, 86, 95, 111, 127, 143, 160, 179, 201, 227, 276};

// Specialized body: pairs p in [CHUNK_B[C], CHUNK_B[C+1]). Zero LDS reads:
// e[] is registers (static indices after unroll), g2/g3 at constexpr offsets
// from kernarg base -> s_load stream. C is BLOCK-uniform, so each CU holds
// only the 1-2 bodies of its resident blocks (I$ fits, unlike wave-per-chunk).
template <int C>
__device__ __forceinline__ float chunk_compute(const float (&e)[F],
                                               const float* __restrict__ g2,
                                               const float* __restrict__ g3) {
    constexpr int P0 = CHUNK_B[C], P1 = CHUNK_B[C + 1];
    float acc = 0.f;
#pragma unroll
    for (int i = 0; i < 23; ++i) {
#pragma unroll
        for (int j = i + 1; j < F; ++j) {
            if (pair_idx(i, j) >= P0 && pair_idx(i, j) < P1) {   // folds at compile time
                float pij = e[i] * e[j];
                acc = fmaf(g2[pair_idx(i, j)], pij, acc);        // 2nd-order
                float s = 0.f;
#pragma unroll
                for (int k = j + 1; k < F; ++k)                  // contiguous trip ids
                    s = fmaf(g3[trip_idx(i, j, k)], e[k], s);
                acc = fmaf(pij, s, acc);                         // 3rd-order
            }
        }
    }
    return acc;
}

// Block = 1024 thr = 16 waves x (16 d x 4 r) = 64 rows, ONE chunk per block
// (chunk = blockIdx & 15 -> scalar CF, 1 body per block). No LDS, no barrier.
__global__ __launch_bounds__(1024, 4) void ctr_partial(
    const int* __restrict__ x, const float* __restrict__ emb,
    const float* __restrict__ lw, const float* __restrict__ g2,
    const float* __restrict__ g3, float* __restrict__ ws) {
    const int bid = blockIdx.x;
    const int chunk = bid & 15;                    // block-uniform (SGPR)
    const int row0 = (bid >> 4) * 64;

    const int tid = threadIdx.x;
    const int d = tid & 15;
    const int r = (tid >> 4) & 3;
    const int w = tid >> 6;
    const int row = row0 + w * 4 + r;

    int xi[F];                                     // own x row: 6 coalesced int4
    {
        const int4* xp = reinterpret_cast<const int4*>(x + row * F);
#pragma unroll
        for (int n = 0; n < 6; ++n) {
            int4 v = xp[n];
            xi[4 * n] = v.x; xi[4 * n + 1] = v.y; xi[4 * n + 2] = v.z; xi[4 * n + 3] = v.w;
        }
    }

    float e[F];                                    // 24 coalesced loads (4x64B segs/instr)
#pragma unroll
    for (int f = 0; f < F; ++f)
        e[f] = emb[(xi[f] + f * VOCAB) * D + d];

    float acc;
    switch (chunk) {                               // block-uniform scalar branch
        case 0:  acc = chunk_compute<0>(e, g2, g3); break;
        case 1:  acc = chunk_compute<1>(e, g2, g3); break;
        case 2:  acc = chunk_compute<2>(e, g2, g3); break;
        case 3:  acc = chunk_compute<3>(e, g2, g3); break;
        case 4:  acc = chunk_compute<4>(e, g2, g3); break;
        case 5:  acc = chunk_compute<5>(e, g2, g3); break;
        case 6:  acc = chunk_compute<6>(e, g2, g3); break;
        case 7:  acc = chunk_compute<7>(e, g2, g3); break;
        case 8:  acc = chunk_compute<8>(e, g2, g3); break;
        case 9:  acc = chunk_compute<9>(e, g2, g3); break;
        case 10: acc = chunk_compute<10>(e, g2, g3); break;
        case 11: acc = chunk_compute<11>(e, g2, g3); break;
        case 12: acc = chunk_compute<12>(e, g2, g3); break;
        case 13: acc = chunk_compute<13>(e, g2, g3); break;
        case 14: acc = chunk_compute<14>(e, g2, g3); break;
        default: acc = chunk_compute<15>(e, g2, g3); break;
    }

    // reduce over the 16 d-lanes (masks 1,2,4,8 stay within each 16-lane group)
#pragma unroll
    for (int m = 1; m < 16; m <<= 1) acc += __shfl_xor(acc, m, 64);

    if (chunk == 15) {                             // fold linear term into chunk 15
        float lin = 0.f;
#pragma unroll
        for (int f = 0; f < F; ++f) lin += lw[xi[f] + f * VOCAB];
        acc += lin;                                // every lane has lin; d==0 stores
    }
    if (d == 0) ws[row * 16 + chunk] = acc;
}

__global__ __launch_bounds__(256) void ctr_final(const float* __restrict__ ws,
                                                 const float* __restrict__ lb,
                                                 float* __restrict__ out) {
    const int row = blockIdx.x * 256 + threadIdx.x;
    const float4* p = reinterpret_cast<const float4*>(ws + row * 16);
    float4 a = p[0], b = p[1], c = p[2], q = p[3];
    float z = ((a.x + a.y) + (a.z + a.w)) + ((b.x + b.y) + (b.z + b.w)) +
              ((c.x + c.y) + (c.z + c.w)) + ((q.x + q.y) + (q.z + q.w)) + lb[0];
    out[row] = 1.f / (1.f + __expf(-z));
}

extern "C" void kernel_launch(void* const* d_in, const int* in_sizes, int n_in,
                              void* d_out, int out_size, void* d_ws, size_t ws_size,
                              hipStream_t stream) {
    const int*   x   = (const int*)d_in[0];
    const float* emb = (const float*)d_in[1];
    const float* lw  = (const float*)d_in[2];
    const float* lb  = (const float*)d_in[3];
    const float* g2  = (const float*)d_in[4];
    const float* g3  = (const float*)d_in[5];
    float* out = (float*)d_out;
    float* ws  = (float*)d_ws;                     // 2048 x 16 partials = 128 KB

    hipLaunchKernelGGL(ctr_partial, dim3((BATCH / 64) * 16), dim3(1024), 0, stream,
                       x, emb, lw, g2, g3, ws);
    hipLaunchKernelGGL(ctr_final, dim3(BATCH / 256), dim3(256), 0, stream,
                       ws, lb, out);
}

// Round 12
// 19.579 us; speedup vs baseline: 1.7174x; 1.7174x over previous
//
#include <hip/hip_runtime.h>
#include <math.h>

#define F 24
#define D 16
#define BATCH 2048
#define NPAIR 276
#define NTRIP 2024
#define VOCAB 10000
#define SLAB 456            // dwords per row slab [d*28+f]; 456%32==8 -> <=2-way alias
#define LONG_SLOTS 80       // 16 waves x 5 (66 real + 14 zero dummies)
#define SHORT_SLOTS 224     // 16 waves x 14 (210 real + 14 zero dummies)
#define LONG_F (LONG_SLOTS * 28)                 // 2240 floats
#define CW_FLOATS (LONG_F + SHORT_SLOTS * 16)    // 5824 floats = 23.3 KB

// ---- index algebra for lexicographic combinations ----
__host__ __device__ constexpr int pair_base(int i) { return i * 23 - i * (i - 1) / 2; }
__host__ __device__ constexpr int trip_base(int i) {
    return NTRIP - (24 - i) * (23 - i) * (22 - i) / 6;
}
__host__ __device__ constexpr int trip_idx(int i, int j, int k) {
    return trip_base(i) + (j - i - 1) * (46 - i - j) / 2 + (k - j - 1);
}
// long tier: pairs with j<=11, rank base per i (i in 0..10)
__device__ __forceinline__ int lbase(int i) { return 11 * i - i * (i - 1) / 2; }
// short tier: pairs with j>=12; ranks 0..143 are i<=11 (12 per i), then triangular
__device__ __forceinline__ int sbase(int i) { return 144 + (35 - i) * (i - 12) / 2; }

__device__ __forceinline__ void ij_of_long(int q, int& i, int& j) {
    if (q >= 66) { i = 0; j = 0; return; }       // dummy (all-zero coefs)
    i = 0;
    while (lbase(i + 1) <= q) ++i;
    j = i + 1 + (q - lbase(i));
}
__device__ __forceinline__ void ij_of_short(int q, int& i, int& j) {
    if (q >= 210) { i = 0; j = 0; return; }      // dummy
    if (q < 144) { i = q / 12; j = 12 + (q - 12 * i); return; }
    i = 12;
    while (sbase(i + 1) <= q) ++i;
    j = i + 1 + (q - sbase(i));
}

// ---- prep: parallel repack, one thread per output float ----
// long slot (j<=11), 28 floats: [i, j, g2, FLAG, c0..c23]  (c_k = coef of e[k])
// short slot (j>=12), 16 floats: [i, j, g2, c13, c14..c23, 0, FLAG]
// FLAG=1 -> this slot's i equals previous slot's i within the same wave's range
// (slots are i-sorted), so ctr_main can skip re-reading e_i from LDS.
__global__ __launch_bounds__(256) void repack_kernel(const float* __restrict__ g2,
                                                     const float* __restrict__ g3,
                                                     float* __restrict__ cw) {
    const int t = blockIdx.x * 256 + threadIdx.x;
    if (t >= CW_FLOATS) return;
    float v = 0.f;
    if (t < LONG_F) {
        const int slot = t / 28, field = t - slot * 28;
        int i, j;
        ij_of_long(slot, i, j);
        const bool real = slot < 66;
        if (field == 0) v = __int_as_float(i);
        else if (field == 1) v = __int_as_float(j);
        else if (field == 2) { if (real) v = g2[pair_base(i) + (j - i - 1)]; }
        else if (field == 3) {                    // FLAG: same-i as prev, not wave start
            int ip, jp;
            if (slot % 5 != 0) { ij_of_long(slot - 1, ip, jp); if (ip == i) v = __int_as_float(1); }
        } else {
            const int k = field - 4;
            if (real && k > j) v = g3[trip_idx(i, j, k)];
        }
    } else {
        const int tt = t - LONG_F;
        const int slot = tt / 16, field = tt - slot * 16;
        int i, j;
        ij_of_short(slot, i, j);
        const bool real = slot < 210;
        if (field == 0) v = __int_as_float(i);
        else if (field == 1) v = __int_as_float(j);
        else if (field == 2) { if (real) v = g2[pair_base(i) + (j - i - 1)]; }
        else if (field >= 3 && field <= 13) {
            const int k = 10 + field;             // c13..c23
            if (real && k > j) v = g3[trip_idx(i, j, k)];
        } else if (field == 15) {                 // FLAG
            int ip, jp;
            if (slot % 14 != 0) { ij_of_short(slot - 1, ip, jp); if (ip == i) v = __int_as_float(1); }
        }
    }
    cw[t] = v;
}

// Block = 1024 thr = 16 waves x (16 d x 4 rows). Wave w (SGPR) owns long slots
// [5w,5w+5) and short slots [14w,14w+14). Uniform body, scalar coef stream.
// e-slab [r][d*28+f]: e-copy = 6x ds_read_b128; ei reads hoisted via FLAG.
__global__ __launch_bounds__(1024, 4) void ctr_main(
    const int* __restrict__ x, const float* __restrict__ emb,
    const float* __restrict__ lw, const float* __restrict__ lb,
    const float* __restrict__ cw, float* __restrict__ out) {
    __shared__ float s_e[4 * SLAB];       // [r][d*28 + f]
    __shared__ float s_lw[4 * F];
    __shared__ float s_part[16][4];       // [chunk][row]

    const int tid = threadIdx.x;
    const int row0 = blockIdx.x * 4;

    if (tid < 4 * F * 4) {                // 384 thr: emb gather, own x load, 1 round
        const int seg = tid >> 2, q = tid & 3;
        const int r = seg / F, f = seg - r * F;
        const int idx = x[(row0 + r) * F + f] + f * VOCAB;
        float4 v = reinterpret_cast<const float4*>(emb)[idx * 4 + q];
        float* b = &s_e[r * SLAB + f];    // dim (4q+m) -> offset (4q+m)*28
        b[(q * 4 + 0) * 28] = v.x;
        b[(q * 4 + 1) * 28] = v.y;
        b[(q * 4 + 2) * 28] = v.z;
        b[(q * 4 + 3) * 28] = v.w;
    } else if (tid < 4 * F * 4 + 4 * F) { // 96 thr: linear-weight gather
        const int tt = tid - 4 * F * 4;
        const int r = tt / F, f = tt - r * F;
        s_lw[tt] = lw[x[(row0 + r) * F + f] + f * VOCAB];
    }
    __syncthreads();

    const int d = tid & 15;
    const int r = (tid >> 4) & 3;
    const int w = __builtin_amdgcn_readfirstlane(tid >> 6);   // SGPR chunk id
    const float* sed = &s_e[r * SLAB + d * 28];               // sed[f] = e[f]

    float e[F];                           // 6x conflict-free ds_read_b128 (f contig)
    {
        const float4* se4 = reinterpret_cast<const float4*>(sed);
#pragma unroll
        for (int n = 0; n < 6; ++n) {
            float4 v = se4[n];
            e[4 * n] = v.x; e[4 * n + 1] = v.y; e[4 * n + 2] = v.z; e[4 * n + 3] = v.w;
        }
    }

    float acc = 0.f;

    const float4* Lp = reinterpret_cast<const float4*>(cw) + w * (5 * 7);
    float eiL = 0.f;                      // carried e_i (FLAG-hoisted)
#pragma unroll 2
    for (int s = 0; s < 5; ++s) {         // long tier: 22-FMA absolute dot
        float4 h  = Lp[s * 7 + 0];
        float4 c0 = Lp[s * 7 + 1], c1 = Lp[s * 7 + 2], c2 = Lp[s * 7 + 3];
        float4 c3 = Lp[s * 7 + 4], c4 = Lp[s * 7 + 5], c5 = Lp[s * 7 + 6];
        int i = __float_as_int(h.x), j = __float_as_int(h.y);
        if (!__float_as_int(h.w)) eiL = sed[i];   // reload only when i changes
        float ej = sed[j];
        float ta = h.z, tb = 0.f;         // seeded with g2; two chains for ILP
        ta = fmaf(c0.z, e[2],  ta); tb = fmaf(c0.w, e[3],  tb);   // c0,c1 == 0 always
        ta = fmaf(c1.x, e[4],  ta); tb = fmaf(c1.y, e[5],  tb);
        ta = fmaf(c1.z, e[6],  ta); tb = fmaf(c1.w, e[7],  tb);
        ta = fmaf(c2.x, e[8],  ta); tb = fmaf(c2.y, e[9],  tb);
        ta = fmaf(c2.z, e[10], ta); tb = fmaf(c2.w, e[11], tb);
        ta = fmaf(c3.x, e[12], ta); tb = fmaf(c3.y, e[13], tb);
        ta = fmaf(c3.z, e[14], ta); tb = fmaf(c3.w, e[15], tb);
        ta = fmaf(c4.x, e[16], ta); tb = fmaf(c4.y, e[17], tb);
        ta = fmaf(c4.z, e[18], ta); tb = fmaf(c4.w, e[19], tb);
        ta = fmaf(c5.x, e[20], ta); tb = fmaf(c5.y, e[21], tb);
        ta = fmaf(c5.z, e[22], ta); tb = fmaf(c5.w, e[23], tb);
        acc = fmaf(eiL * ej, ta + tb, acc);
    }

    const float4* Sp = reinterpret_cast<const float4*>(cw) + (LONG_F / 4) + w * (14 * 4);
    float eiS = 0.f;
#pragma unroll 2
    for (int s = 0; s < 14; ++s) {        // short tier: 11-FMA dot over e[13..23]
        float4 h  = Sp[s * 4 + 0];
        float4 k0 = Sp[s * 4 + 1], k1 = Sp[s * 4 + 2], k2 = Sp[s * 4 + 3];
        int i = __float_as_int(h.x), j = __float_as_int(h.y);
        if (!__float_as_int(k2.w)) eiS = sed[i];  // reload only when i changes
        float ej = sed[j];
        float ta = h.z, tb = 0.f;
        ta = fmaf(h.w,  e[13], ta);
        tb = fmaf(k0.x, e[14], tb); ta = fmaf(k0.y, e[15], ta);
        tb = fmaf(k0.z, e[16], tb); ta = fmaf(k0.w, e[17], ta);
        tb = fmaf(k1.x, e[18], tb); ta = fmaf(k1.y, e[19], ta);
        tb = fmaf(k1.z, e[20], tb); ta = fmaf(k1.w, e[21], ta);
        tb = fmaf(k2.x, e[22], tb); ta = fmaf(k2.y, e[23], ta);
        acc = fmaf(eiS * ej, ta + tb, acc);
    }

    // reduce over the 16 d-lanes (masks stay within each 16-lane group)
#pragma unroll
    for (int m = 1; m < 16; m <<= 1) acc += __shfl_xor(acc, m, 64);
    if (d == 0) s_part[w][r] = acc;
    __syncthreads();

    if (tid < 64) {                       // rr = row, c = chunk (lane bits 0..3)
        const int rr = tid >> 4, c = tid & 15;
        float v = s_part[c][rr];
#pragma unroll
        for (int m = 1; m < 16; m <<= 1) v += __shfl_xor(v, m, 64);
        if (c == 0) {
            float lin = lb[0];
#pragma unroll
            for (int f = 0; f < F; ++f) lin += s_lw[rr * F + f];
            float z = v + lin;
            out[row0 + rr] = 1.f / (1.f + __expf(-z));
        }
    }
}

extern "C" void kernel_launch(void* const* d_in, const int* in_sizes, int n_in,
                              void* d_out, int out_size, void* d_ws, size_t ws_size,
                              hipStream_t stream) {
    const int*   x   = (const int*)d_in[0];
    const float* emb = (const float*)d_in[1];
    const float* lw  = (const float*)d_in[2];
    const float* lb  = (const float*)d_in[3];
    const float* g2  = (const float*)d_in[4];
    const float* g3  = (const float*)d_in[5];
    float* out = (float*)d_out;
    float* cw  = (float*)d_ws;            // 2-tier slot table + flags, 23.3 KB

    hipLaunchKernelGGL(repack_kernel, dim3((CW_FLOATS + 255) / 256), dim3(256), 0, stream,
                       g2, g3, cw);
    hipLaunchKernelGGL(ctr_main, dim3(BATCH / 4), dim3(1024), 0, stream,
                       x, emb, lw, lb, cw, out);
}

// Round 13
// 19.559 us; speedup vs baseline: 1.7192x; 1.0010x over previous
//
#include <hip/hip_runtime.h>
#include <math.h>

#define F 24
#define D 16
#define BATCH 2048
#define NPAIR 276
#define NTRIP 2024
#define VOCAB 10000
#define SLAB 392            // floats per row slab [f*16+d]: 2-way bank alias max (free)
#define LONG_SLOTS 80       // 16 waves x 5 (66 real + 14 zero dummies)
#define SHORT_SLOTS 224     // 16 waves x 14 (210 real + 14 zero dummies)
#define LONG_F (LONG_SLOTS * 28)                 // 2240 floats
#define CW_FLOATS (LONG_F + SHORT_SLOTS * 16)    // 5824 floats = 23.3 KB

// ---- index algebra for lexicographic combinations ----
__host__ __device__ constexpr int pair_base(int i) { return i * 23 - i * (i - 1) / 2; }
__host__ __device__ constexpr int trip_base(int i) {
    return NTRIP - (24 - i) * (23 - i) * (22 - i) / 6;
}
__host__ __device__ constexpr int trip_idx(int i, int j, int k) {
    return trip_base(i) + (j - i - 1) * (46 - i - j) / 2 + (k - j - 1);
}
// long tier: pairs with j<=11, rank base per i (i in 0..10)
__device__ __forceinline__ int lbase(int i) { return 11 * i - i * (i - 1) / 2; }
// short tier: pairs with j>=12; ranks 0..143 are i<=11 (12 per i), then triangular
__device__ __forceinline__ int sbase(int i) { return 144 + (35 - i) * (i - 12) / 2; }

__device__ __forceinline__ void ij_of_long(int q, int& i, int& j) {
    if (q >= 66) { i = 0; j = 0; return; }       // dummy (all-zero coefs)
    i = 0;
    while (lbase(i + 1) <= q) ++i;
    j = i + 1 + (q - lbase(i));
}
__device__ __forceinline__ void ij_of_short(int q, int& i, int& j) {
    if (q >= 210) { i = 0; j = 0; return; }      // dummy
    if (q < 144) { i = q / 12; j = 12 + (q - 12 * i); return; }
    i = 12;
    while (sbase(i + 1) <= q) ++i;
    j = i + 1 + (q - sbase(i));
}

// ---- prep: parallel repack, one thread per output float ----
// long slot (j<=11), 28 floats: [i, j, g2, FLAG, c0..c23]  (c_k = coef of e[k])
// short slot (j>=12), 16 floats: [i, j, g2, c13, c14..c23, 0, FLAG]
// FLAG=1 -> same i as previous slot in this wave's range (slots i-sorted),
// so ctr_main skips re-reading e_i from LDS (scalar-guarded).
__global__ __launch_bounds__(256) void repack_kernel(const float* __restrict__ g2,
                                                     const float* __restrict__ g3,
                                                     float* __restrict__ cw) {
    const int t = blockIdx.x * 256 + threadIdx.x;
    if (t >= CW_FLOATS) return;
    float v = 0.f;
    if (t < LONG_F) {
        const int slot = t / 28, field = t - slot * 28;
        int i, j;
        ij_of_long(slot, i, j);
        const bool real = slot < 66;
        if (field == 0) v = __int_as_float(i);
        else if (field == 1) v = __int_as_float(j);
        else if (field == 2) { if (real) v = g2[pair_base(i) + (j - i - 1)]; }
        else if (field == 3) {                    // FLAG (was always 0 -> layout-compat)
            int ip, jp;
            if (slot % 5 != 0) { ij_of_long(slot - 1, ip, jp); if (ip == i) v = __int_as_float(1); }
        } else {
            const int k = field - 4;
            if (real && k > j) v = g3[trip_idx(i, j, k)];
        }
    } else {
        const int tt = t - LONG_F;
        const int slot = tt / 16, field = tt - slot * 16;
        int i, j;
        ij_of_short(slot, i, j);
        const bool real = slot < 210;
        if (field == 0) v = __int_as_float(i);
        else if (field == 1) v = __int_as_float(j);
        else if (field == 2) { if (real) v = g2[pair_base(i) + (j - i - 1)]; }
        else if (field >= 3 && field <= 13) {
            const int k = 10 + field;             // c13..c23
            if (real && k > j) v = g3[trip_idx(i, j, k)];
        } else if (field == 15) {                 // FLAG
            int ip, jp;
            if (slot % 14 != 0) { ij_of_short(slot - 1, ip, jp); if (ip == i) v = __int_as_float(1); }
        }
    }
    cw[t] = v;
}

// Block = 1024 thr = 16 waves x (16 d x 4 rows). Wave w (SGPR) owns long slots
// [5w,5w+5) and short slots [14w,14w+14). Uniform body, scalar coef stream.
// Layout [f*16+d], SLAB 392: every LDS access <=2-way bank alias (free).
__global__ __launch_bounds__(1024, 4) void ctr_main(
    const int* __restrict__ x, const float* __restrict__ emb,
    const float* __restrict__ lw, const float* __restrict__ lb,
    const float* __restrict__ cw, float* __restrict__ out) {
    __shared__ float s_e[4 * SLAB];       // [r][f*16 + d]
    __shared__ float s_lw[4 * F];
    __shared__ float s_part[16][4];       // [chunk][row]

    const int tid = threadIdx.x;
    const int row0 = blockIdx.x * 4;

    if (tid < 4 * F * 4) {                // 384 thr: emb gather, own x load, 1 round
        const int seg = tid >> 2, q = tid & 3;
        const int r = seg / F, f = seg - r * F;
        const int idx = x[(row0 + r) * F + f] + f * VOCAB;
        float4 v = reinterpret_cast<const float4*>(emb)[idx * 4 + q];
        float* b = &s_e[r * SLAB + f * D + q * 4];
        b[0] = v.x; b[1] = v.y; b[2] = v.z; b[3] = v.w;
    } else if (tid < 4 * F * 4 + 4 * F) { // 96 thr: linear-weight gather, own x load
        const int tt = tid - 4 * F * 4;
        const int r = tt / F, f = tt - r * F;
        s_lw[tt] = lw[x[(row0 + r) * F + f] + f * VOCAB];
    }
    __syncthreads();

    const int d = tid & 15;
    const int r = (tid >> 4) & 3;
    const int w = __builtin_amdgcn_readfirstlane(tid >> 6);   // SGPR chunk id
    const float* se = &s_e[r * SLAB];

    float e[F];                           // only e[2..23] are statically referenced
#pragma unroll
    for (int f = 2; f < F; ++f) e[f] = se[f * D + d];   // 22x b32, 2-way free

    float acc = 0.f;

    const float4* Lp = reinterpret_cast<const float4*>(cw) + w * (5 * 7);
    float eiL = 0.f;                      // carried e_i (FLAG-hoisted, scalar guard)
#pragma unroll 2
    for (int s = 0; s < 5; ++s) {         // long tier: 22-FMA absolute dot
        float4 h  = Lp[s * 7 + 0];
        float4 c0 = Lp[s * 7 + 1], c1 = Lp[s * 7 + 2], c2 = Lp[s * 7 + 3];
        float4 c3 = Lp[s * 7 + 4], c4 = Lp[s * 7 + 5], c5 = Lp[s * 7 + 6];
        int i = __float_as_int(h.x), j = __float_as_int(h.y);
        if (!__float_as_int(h.w)) eiL = se[i * D + d];   // reload only when i changes
        float ej = se[j * D + d];
        float ta = h.z, tb = 0.f;         // seeded with g2; two chains for ILP
        ta = fmaf(c0.z, e[2],  ta); tb = fmaf(c0.w, e[3],  tb);   // c0,c1 == 0 always
        ta = fmaf(c1.x, e[4],  ta); tb = fmaf(c1.y, e[5],  tb);
        ta = fmaf(c1.z, e[6],  ta); tb = fmaf(c1.w, e[7],  tb);
        ta = fmaf(c2.x, e[8],  ta); tb = fmaf(c2.y, e[9],  tb);
        ta = fmaf(c2.z, e[10], ta); tb = fmaf(c2.w, e[11], tb);
        ta = fmaf(c3.x, e[12], ta); tb = fmaf(c3.y, e[13], tb);
        ta = fmaf(c3.z, e[14], ta); tb = fmaf(c3.w, e[15], tb);
        ta = fmaf(c4.x, e[16], ta); tb = fmaf(c4.y, e[17], tb);
        ta = fmaf(c4.z, e[18], ta); tb = fmaf(c4.w, e[19], tb);
        ta = fmaf(c5.x, e[20], ta); tb = fmaf(c5.y, e[21], tb);
        ta = fmaf(c5.z, e[22], ta); tb = fmaf(c5.w, e[23], tb);
        acc = fmaf(eiL * ej, ta + tb, acc);
    }

    const float4* Sp = reinterpret_cast<const float4*>(cw) + (LONG_F / 4) + w * (14 * 4);
    float eiS = 0.f;
#pragma unroll 2
    for (int s = 0; s < 14; ++s) {        // short tier: 11-FMA dot over e[13..23]
        float4 h  = Sp[s * 4 + 0];
        float4 k0 = Sp[s * 4 + 1], k1 = Sp[s * 4 + 2], k2 = Sp[s * 4 + 3];
        int i = __float_as_int(h.x), j = __float_as_int(h.y);
        if (!__float_as_int(k2.w)) eiS = se[i * D + d];  // FLAG in field 15
        float ej = se[j * D + d];
        float ta = h.z, tb = 0.f;
        ta = fmaf(h.w,  e[13], ta);
        tb = fmaf(k0.x, e[14], tb); ta = fmaf(k0.y, e[15], ta);
        tb = fmaf(k0.z, e[16], tb); ta = fmaf(k0.w, e[17], ta);
        tb = fmaf(k1.x, e[18], tb); ta = fmaf(k1.y, e[19], ta);
        tb = fmaf(k1.z, e[20], tb); ta = fmaf(k1.w, e[21], ta);
        tb = fmaf(k2.x, e[22], tb); ta = fmaf(k2.y, e[23], ta);
        acc = fmaf(eiS * ej, ta + tb, acc);
    }

    // reduce over the 16 d-lanes (masks stay within each 16-lane group)
#pragma unroll
    for (int m = 1; m < 16; m <<= 1) acc += __shfl_xor(acc, m, 64);
    if (d == 0) s_part[w][r] = acc;
    __syncthreads();

    if (tid < 64) {                       // rr = row, c = chunk (lane bits 0..3)
        const int rr = tid >> 4, c = tid & 15;
        float v = s_part[c][rr];
#pragma unroll
        for (int m = 1; m < 16; m <<= 1) v += __shfl_xor(v, m, 64);
        if (c == 0) {
            float lin = lb[0];
#pragma unroll
            for (int f = 0; f < F; ++f) lin += s_lw[rr * F + f];
            float z = v + lin;
            out[row0 + rr] = 1.f / (1.f + __expf(-z));
        }
    }
}

extern "C" void kernel_launch(void* const* d_in, const int* in_sizes, int n_in,
                              void* d_out, int out_size, void* d_ws, size_t ws_size,
                              hipStream_t stream) {
    const int*   x   = (const int*)d_in[0];
    const float* emb = (const float*)d_in[1];
    const float* lw  = (const float*)d_in[2];
    const float* lb  = (const float*)d_in[3];
    const float* g2  = (const float*)d_in[4];
    const float* g3  = (const float*)d_in[5];
    float* out = (float*)d_out;
    float* cw  = (float*)d_ws;            // 2-tier slot table + flags, 23.3 KB

    hipLaunchKernelGGL(repack_kernel, dim3((CW_FLOATS + 255) / 256), dim3(256), 0, stream,
                       g2, g3, cw);
    hipLaunchKernelGGL(ctr_main, dim3(BATCH / 4), dim3(1024), 0, stream,
                       x, emb, lw, lb, cw, out);
}

// Round 14
// 17.169 us; speedup vs baseline: 1.9585x; 1.1392x over previous
//
#include <hip/hip_runtime.h>
#include <math.h>

#define F 24
#define D 16
#define BATCH 2048
#define NPAIR 276
#define NTRIP 2024
#define VOCAB 10000
#define SLAB 392            // floats per row slab [f*16+d]: 2-way bank alias max (free)
#define LONG_SLOTS 80       // 16 waves x 5 (66 real + 14 zero dummies)
#define SHORT_SLOTS 224     // 16 waves x 14 (210 real + 14 zero dummies)
#define LONG_F (LONG_SLOTS * 28)                 // 2240 floats
#define CW_FLOATS (LONG_F + SHORT_SLOTS * 16)    // 5824 floats = 23.3 KB

// ---- index algebra for lexicographic combinations ----
__host__ __device__ constexpr int pair_base(int i) { return i * 23 - i * (i - 1) / 2; }
__host__ __device__ constexpr int trip_base(int i) {
    return NTRIP - (24 - i) * (23 - i) * (22 - i) / 6;
}
__host__ __device__ constexpr int trip_idx(int i, int j, int k) {
    return trip_base(i) + (j - i - 1) * (46 - i - j) / 2 + (k - j - 1);
}
// long tier: pairs with j<=11, rank base per i
__device__ __forceinline__ int lbase(int i) { return 11 * i - i * (i - 1) / 2; }
// short tier: pairs with j>=12; ranks 0..143 are i<=11 (12 per i), then triangular
__device__ __forceinline__ int sbase(int i) { return 144 + (35 - i) * (i - 12) / 2; }

// ---- prep: fully parallel repack, ONE THREAD PER OUTPUT FLOAT (~0.5 us) ----
// long slot (j<=11), 28 floats: [i, j, g2, 0, c0..c23]  (c_k = coef of e[k])
// short slot (j>=12), 16 floats: [i, j, g2, c13..c23, 0, 0] (field 3+m = coef e[13+m])
__global__ __launch_bounds__(256) void repack_kernel(const float* __restrict__ g2,
                                                     const float* __restrict__ g3,
                                                     float* __restrict__ cw) {
    const int t = blockIdx.x * 256 + threadIdx.x;
    if (t >= CW_FLOATS) return;
    float v = 0.f;
    if (t < LONG_F) {
        const int slot = t / 28, field = t - slot * 28;
        if (slot < 66) {                          // real long slot
            int i = 0;
            while (lbase(i + 1) <= slot) ++i;     // i in 0..10
            const int j = i + 1 + (slot - lbase(i));
            if (field == 0) v = __int_as_float(i);
            else if (field == 1) v = __int_as_float(j);
            else if (field == 2) v = g2[pair_base(i) + (j - i - 1)];
            else if (field >= 4) {
                const int k = field - 4;
                if (k > j) v = g3[trip_idx(i, j, k)];
            }
        }
    } else {
        const int tt = t - LONG_F;
        const int slot = tt / 16, field = tt - slot * 16;
        if (slot < 210) {                         // real short slot
            int i, j;
            if (slot < 144) { i = slot / 12; j = 12 + (slot - 12 * i); }
            else { i = 12; while (sbase(i + 1) <= slot) ++i; j = i + 1 + (slot - sbase(i)); }
            if (field == 0) v = __int_as_float(i);
            else if (field == 1) v = __int_as_float(j);
            else if (field == 2) v = g2[pair_base(i) + (j - i - 1)];
            else if (field >= 3 && field <= 13) {
                const int k = 10 + field;         // e[13]..e[23]
                if (k > j) v = g3[trip_idx(i, j, k)];
            }
        }
    }
    cw[t] = v;
}

// Block = 1024 thr = 16 waves x (16 d x 4 rows). Wave w (SGPR) owns long slots
// [5w,5w+5) and short slots [14w,14w+14). Uniform body, scalar coef stream.
// Staging: ONE barrier (each gather thread re-loads its own x scalar).
__global__ __launch_bounds__(1024, 4) void ctr_main(
    const int* __restrict__ x, const float* __restrict__ emb,
    const float* __restrict__ lw, const float* __restrict__ lb,
    const float* __restrict__ cw, float* __restrict__ out) {
    __shared__ float s_e[4 * SLAB];       // [r][f*16 + d]
    __shared__ float s_lw[4 * F];
    __shared__ float s_part[16][4];       // [chunk][row]

    const int tid = threadIdx.x;
    const int row0 = blockIdx.x * 4;

    if (tid < 4 * F * 4) {                // 384 thr: emb gather, own x load, 1 round
        const int seg = tid >> 2, q = tid & 3;
        const int r = seg / F, f = seg - r * F;
        const int idx = x[(row0 + r) * F + f] + f * VOCAB;
        float4 v = reinterpret_cast<const float4*>(emb)[idx * 4 + q];
        float* b = &s_e[r * SLAB + f * D + q * 4];
        b[0] = v.x; b[1] = v.y; b[2] = v.z; b[3] = v.w;
    } else if (tid < 4 * F * 4 + 4 * F) { // 96 thr: linear-weight gather, own x load
        const int tt = tid - 4 * F * 4;
        const int r = tt / F, f = tt - r * F;
        s_lw[tt] = lw[x[(row0 + r) * F + f] + f * VOCAB];
    }
    __syncthreads();

    const int d = tid & 15;
    const int r = (tid >> 4) & 3;
    const int w = __builtin_amdgcn_readfirstlane(tid >> 6);   // SGPR chunk id
    const float* se = &s_e[r * SLAB];

    float e[F];                           // register copy, statically indexed only
#pragma unroll
    for (int f = 0; f < F; ++f) e[f] = se[f * D + d];

    float acc = 0.f;

    const float4* Lp = reinterpret_cast<const float4*>(cw) + w * (5 * 7);
#pragma unroll 2
    for (int s = 0; s < 5; ++s) {         // long tier: 22-FMA absolute dot
        float4 h  = Lp[s * 7 + 0];
        float4 c0 = Lp[s * 7 + 1], c1 = Lp[s * 7 + 2], c2 = Lp[s * 7 + 3];
        float4 c3 = Lp[s * 7 + 4], c4 = Lp[s * 7 + 5], c5 = Lp[s * 7 + 6];
        int i = __float_as_int(h.x), j = __float_as_int(h.y);
        float ei = se[i * D + d];         // runtime index -> LDS (2-way alias, free)
        float ej = se[j * D + d];
        float ta = h.z, tb = 0.f;         // seeded with g2; two chains for ILP
        ta = fmaf(c0.z, e[2],  ta); tb = fmaf(c0.w, e[3],  tb);   // c0,c1 == 0 always
        ta = fmaf(c1.x, e[4],  ta); tb = fmaf(c1.y, e[5],  tb);
        ta = fmaf(c1.z, e[6],  ta); tb = fmaf(c1.w, e[7],  tb);
        ta = fmaf(c2.x, e[8],  ta); tb = fmaf(c2.y, e[9],  tb);
        ta = fmaf(c2.z, e[10], ta); tb = fmaf(c2.w, e[11], tb);
        ta = fmaf(c3.x, e[12], ta); tb = fmaf(c3.y, e[13], tb);
        ta = fmaf(c3.z, e[14], ta); tb = fmaf(c3.w, e[15], tb);
        ta = fmaf(c4.x, e[16], ta); tb = fmaf(c4.y, e[17], tb);
        ta = fmaf(c4.z, e[18], ta); tb = fmaf(c4.w, e[19], tb);
        ta = fmaf(c5.x, e[20], ta); tb = fmaf(c5.y, e[21], tb);
        ta = fmaf(c5.z, e[22], ta); tb = fmaf(c5.w, e[23], tb);
        acc = fmaf(ei * ej, ta + tb, acc);
    }

    const float4* Sp = reinterpret_cast<const float4*>(cw) + (LONG_F / 4) + w * (14 * 4);
#pragma unroll 2
    for (int s = 0; s < 14; ++s) {        // short tier: 11-FMA dot over e[13..23]
        float4 h  = Sp[s * 4 + 0];
        float4 k0 = Sp[s * 4 + 1], k1 = Sp[s * 4 + 2], k2 = Sp[s * 4 + 3];
        int i = __float_as_int(h.x), j = __float_as_int(h.y);
        float ei = se[i * D + d];
        float ej = se[j * D + d];
        float ta = h.z, tb = 0.f;
        ta = fmaf(h.w,  e[13], ta);
        tb = fmaf(k0.x, e[14], tb); ta = fmaf(k0.y, e[15], ta);
        tb = fmaf(k0.z, e[16], tb); ta = fmaf(k0.w, e[17], ta);
        tb = fmaf(k1.x, e[18], tb); ta = fmaf(k1.y, e[19], ta);
        tb = fmaf(k1.z, e[20], tb); ta = fmaf(k1.w, e[21], ta);
        tb = fmaf(k2.x, e[22], tb); ta = fmaf(k2.y, e[23], ta);
        acc = fmaf(ei * ej, ta + tb, acc);
    }

    // reduce over the 16 d-lanes (masks stay within each 16-lane group)
#pragma unroll
    for (int m = 1; m < 16; m <<= 1) acc += __shfl_xor(acc, m, 64);
    if (d == 0) s_part[w][r] = acc;
    __syncthreads();

    if (tid < 64) {                       // rr = row, c = chunk (in lane bits 0..3)
        const int rr = tid >> 4, c = tid & 15;
        float v = s_part[c][rr];
#pragma unroll
        for (int m = 1; m < 16; m <<= 1) v += __shfl_xor(v, m, 64);
        if (c == 0) {
            float lin = lb[0];
#pragma unroll
            for (int f = 0; f < F; ++f) lin += s_lw[rr * F + f];
            float z = v + lin;
            out[row0 + rr] = 1.f / (1.f + __expf(-z));
        }
    }
}

extern "C" void kernel_launch(void* const* d_in, const int* in_sizes, int n_in,
                              void* d_out, int out_size, void* d_ws, size_t ws_size,
                              hipStream_t stream) {
    const int*   x   = (const int*)d_in[0];
    const float* emb = (const float*)d_in[1];
    const float* lw  = (const float*)d_in[2];
    const float* lb  = (const float*)d_in[3];
    const float* g2  = (const float*)d_in[4];
    const float* g3  = (const float*)d_in[5];
    float* out = (float*)d_out;
    float* cw  = (float*)d_ws;            // 2-tier slot table, 23.3 KB

    hipLaunchKernelGGL(repack_kernel, dim3((CW_FLOATS + 255) / 256), dim3(256), 0, stream,
                       g2, g3, cw);
    hipLaunchKernelGGL(ctr_main, dim3(BATCH / 4), dim3(1024), 0, stream,
                       x, emb, lw, lb, cw, out);
}